// Round 4
// baseline (307.301 us; speedup 1.0000x reference)
//
#include <hip/hip_runtime.h>
#include <cstdint>
#include <cstddef>

typedef _Float16 f16;
typedef _Float16 f16x4 __attribute__((ext_vector_type(4)));
typedef _Float16 f16x8 __attribute__((ext_vector_type(8)));
typedef float    f32x4 __attribute__((ext_vector_type(4)));

#define CIN    128
#define COUT   256
#define HH     56
#define WW     56
#define HW     3136           // 56*56
#define PPDIM  3364           // 58*58 padded pixel plane
#define XPLANE (PPDIM*CIN)    // 430592 halves per batch image

__device__ __forceinline__ void gload16(const void* g, void* l) {
  __builtin_amdgcn_global_load_lds((const __attribute__((address_space(1))) unsigned int*)g,
                                   (__attribute__((address_space(3))) unsigned int*)l,
                                   16, 0, 0);
}

// ---------------------------------------------------------------------------
// Prepass 1 (LDS-free): x (NCHW f32) -> zero-padded NHWC f16, incl. all pads.
// ---------------------------------------------------------------------------
__global__ __launch_bounds__(256) void xpad_kernel(const float* __restrict__ x,
                                                   f16* __restrict__ xp) {
  const int bid = blockIdx.x;             // 32*58 = 1856
  const int pr  = bid % 58;
  const int b   = bid / 58;
  const int tid = threadIdx.x;
  f16* orow = xp + (size_t)b * XPLANE + (size_t)pr * 58 * CIN;

  if (pr == 0 || pr == 57) {
    for (int i = tid; i < 928; i += 256)
      *(f16x8*)(orow + (size_t)i * 8) = (f16x8){};
    return;
  }
  const int h = pr - 1;
  const int wave = tid >> 6, lane = tid & 63;
  if (tid < 32) {                         // pad columns px=0 and px=57
    int px = (tid < 16) ? 0 : 57;
    int cg = tid & 15;
    *(f16x8*)(orow + (size_t)px * CIN + cg * 8) = (f16x8){};
  }
  if (lane < 56) {
    const float* xb = x + (size_t)b * CIN * HW + (size_t)h * WW + lane;
    f16* op = orow + (size_t)(lane + 1) * CIN;
    #pragma unroll
    for (int cg = 0; cg < 4; ++cg) {
      const int c0 = (wave * 4 + cg) * 8;
      f16x8 v;
      #pragma unroll
      for (int j = 0; j < 8; ++j)
        v[j] = (f16)xb[(size_t)(c0 + j) * HW];
      *(f16x8*)(op + c0) = v;
    }
  }
}

// ---------------------------------------------------------------------------
// Prepass 2: w (OIHW f32) -> sign -> f16, LINEAR layout (B is now read from
// global/L2 by the main kernel, no LDS, no swizzle):
// wt[s][co][kl], s = K-tile (18 of BK=64), kl in [0,64), c = (s&1)*64 + kl.
// ---------------------------------------------------------------------------
__global__ __launch_bounds__(256) void wprep_kernel(const float* __restrict__ w,
                                                    f16* __restrict__ wt) {
  int t = blockIdx.x * 256 + threadIdx.x;   // 294912 exact
  int s    = t >> 14;
  int hidx = t & 16383;
  int co   = hidx >> 6;
  int kl   = hidx & 63;
  int kidx = s >> 1;
  int c    = ((s & 1) << 6) + kl;
  float v = w[(size_t)co * 1152 + c * 9 + kidx];
  wt[t] = (f16)((v > 0.f) ? 1.f : (v < 0.f ? -1.f : 0.f));
}

// ---------------------------------------------------------------------------
// Main implicit-GEMM: tile 128 px x 256 co, K=1152, 18 K-tiles of BK=64.
// 256 threads = 4 waves (2M x 2N), wave-tile 64 px x 128 co.
// A (x) in LDS, double-buffered 2x16KB, 3-bit XOR swizzle, staged via
// global_load_lds in phases 0-1 of the previous tile (1 barrier per tile).
// B (weights) read per-tile straight from global (L2-hot, 0.59 MB) into regs.
// ---------------------------------------------------------------------------
__global__ __launch_bounds__(256, 2) void bconv_main(
    const f16* __restrict__ xp, const f16* __restrict__ wt,
    const float* __restrict__ bias, float* __restrict__ out) {
  __shared__ __align__(16) f16 Alds[16384];      // 32 KB: 2 buffers x 128rows x 128B
  const int tid = threadIdx.x;
  const int bid = blockIdx.x;                    // 784 = 8*98, XCD swizzle
  const int swz = (bid & 7) * 98 + (bid >> 3);
  const int p0  = swz * 128;

  // ---- staging map: thread fills rows rl, rl+32, rl+64, rl+96 ----
  const int rl   = tid >> 3;                     // 0..31
  const int kx_s = ((tid & 7) << 4) ^ ((rl & 7) << 4);
  const char* srcA[4];
  #pragma unroll
  for (int q = 0; q < 4; ++q) {
    int pg = p0 + q * 32 + rl;
    int b = pg / HW, r = pg % HW;
    int h = r / WW,  w = r % WW;
    srcA[q] = (const char*)xp +
              2 * ((size_t)b * XPLANE + (size_t)((h + 1) * 58 + (w + 1)) * CIN) + kx_s;
  }
  char* AldsB = (char*)Alds;
  const int dst_t = tid << 4;

  // ---- fragment maps ----
  const int wave = tid >> 6, lane = tid & 63;
  const int wm = wave >> 1;        // px half (64)
  const int wn = wave & 1;         // co half (128)
  const int l15 = lane & 15, l4 = lane >> 4;
  const int off0 = (l4 << 4) ^ ((l15 & 7) << 4);           // kk=0 byte off
  const int off1 = (64 + (l4 << 4)) ^ ((l15 & 7) << 4);    // kk=1 byte off
  const int xrow_base = (wm * 64 + l15) << 7;              // byte row base
  const f16* wfp = wt + ((size_t)(wn * 128 + l15) << 6) + (l4 << 3);

  f32x4 acc[8][4];                 // [i: co frag][j: px frag]
  #pragma unroll
  for (int i = 0; i < 8; ++i)
    #pragma unroll
    for (int j = 0; j < 4; ++j) acc[i][j] = (f32x4){0.f, 0.f, 0.f, 0.f};

  // ---- prologue: stage tile 0 (kidx=0 => dh=dw=-1, ch=0) into buf0 ----
  #pragma unroll
  for (int q = 0; q < 4; ++q)
    gload16(srcA[q] - 15104, AldsB + q * 4096 + dst_t);
  __syncthreads();

  auto TILE = [&](int rb, int wb, int TT, long toff, bool dostage) {
    // B fragments for this K-tile from global (L2-hot)
    f16x8 wf[8][2];
    const f16* ws = wfp + ((size_t)TT << 14);
    #pragma unroll
    for (int i = 0; i < 8; ++i) {
      wf[i][0] = *(const f16x8*)(ws + i * 1024);
      wf[i][1] = *(const f16x8*)(ws + i * 1024 + 32);
    }
    #pragma unroll
    for (int j = 0; j < 4; ++j) {
      if (j < 2 && dostage) {
        gload16(srcA[2 * j]     + toff, AldsB + wb + (2 * j) * 4096     + dst_t);
        gload16(srcA[2 * j + 1] + toff, AldsB + wb + (2 * j + 1) * 4096 + dst_t);
      }
      const char* xrow = AldsB + rb + xrow_base + (j << 11);
      f16x8 xf0 = *(const f16x8*)(xrow + off0);
      f16x8 xf1 = *(const f16x8*)(xrow + off1);
      __builtin_amdgcn_s_setprio(1);
      #pragma unroll
      for (int i = 0; i < 8; ++i)
        acc[i][j] = __builtin_amdgcn_mfma_f32_16x16x32_f16(wf[i][0], xf0, acc[i][j], 0, 0, 0);
      #pragma unroll
      for (int i = 0; i < 8; ++i)
        acc[i][j] = __builtin_amdgcn_mfma_f32_16x16x32_f16(wf[i][1], xf1, acc[i][j], 0, 0, 0);
      __builtin_amdgcn_s_setprio(0);
    }
  };

  #pragma unroll 1
  for (int it = 0; it < 9; ++it) {
    const int dh = it / 3 - 1, dw = it % 3 - 1;
    const long toff_o = ((long)(dh * 58 + dw) * 128 + 64) * 2;   // stage 2it+1 (ch=1)
    const int kn = (it < 8) ? (it + 1) : 8;
    const int dh2 = kn / 3 - 1, dw2 = kn % 3 - 1;
    const long toff_e = ((long)(dh2 * 58 + dw2) * 128) * 2;      // stage 2it+2 (ch=0)
    // even tile: read buf0, stage odd tile into buf1
    TILE(0, 16384, 2 * it, toff_o, true);
    __syncthreads();
    // odd tile: read buf1, stage next even tile into buf0
    TILE(16384, 0, 2 * it + 1, toff_e, it < 8);
    __syncthreads();
  }

  // ---- epilogue: D col(l15)=px -> coalesced 64B runs along px ----
  #pragma unroll
  for (int j = 0; j < 4; ++j) {
    const int pg = p0 + wm * 64 + j * 16 + l15;
    const int bo = pg / HW;
    const int pr = pg % HW;
    float* ob = out + (size_t)bo * (COUT * HW) + pr;
    #pragma unroll
    for (int i = 0; i < 8; ++i) {
      const int cb = wn * 128 + i * 16 + l4 * 4;
      #pragma unroll
      for (int r = 0; r < 4; ++r)
        ob[(size_t)(cb + r) * HW] = acc[i][j][r] + bias[cb + r];
    }
  }
}

extern "C" void kernel_launch(void* const* d_in, const int* in_sizes, int n_in,
                              void* d_out, int out_size, void* d_ws, size_t ws_size,
                              hipStream_t stream) {
  const float* x    = (const float*)d_in[0];
  const float* w    = (const float*)d_in[1];
  const float* bias = (const float*)d_in[2];
  float* out = (float*)d_out;

  f16* xp = (f16*)d_ws;                       // 32*430592 halves = 27.56 MB
  f16* wt = xp + (size_t)32 * XPLANE;         // 294912 halves    = 0.59 MB

  xpad_kernel<<<1856, 256, 0, stream>>>(x, xp);
  wprep_kernel<<<1152, 256, 0, stream>>>(w, wt);
  bconv_main<<<784, 256, 0, stream>>>(xp, wt, bias, out);
}

// Round 5
// 258.186 us; speedup vs baseline: 1.1902x; 1.1902x over previous
//
#include <hip/hip_runtime.h>
#include <cstdint>
#include <cstddef>

typedef _Float16 f16;
typedef _Float16 f16x8 __attribute__((ext_vector_type(8)));
typedef float    f32x4 __attribute__((ext_vector_type(4)));

#define CIN    128
#define COUT   256
#define HH     56
#define WW     56
#define HW     3136           // 56*56
#define XPLANE (3364*128)     // 58*58 padded plane * CIN halves

__device__ __forceinline__ void gload16(const void* g, void* l) {
  __builtin_amdgcn_global_load_lds((const __attribute__((address_space(1))) unsigned int*)g,
                                   (__attribute__((address_space(3))) unsigned int*)l,
                                   16, 0, 0);
}

// ---------------------------------------------------------------------------
// Prepass 1 (LDS-free, proven R3): x (NCHW f32) -> zero-padded NHWC f16.
// ---------------------------------------------------------------------------
__global__ __launch_bounds__(256) void xpad_kernel(const float* __restrict__ x,
                                                   f16* __restrict__ xp) {
  const int bid = blockIdx.x;             // 32*58 = 1856
  const int pr  = bid % 58;
  const int b   = bid / 58;
  const int tid = threadIdx.x;
  f16* orow = xp + (size_t)b * XPLANE + (size_t)pr * 58 * CIN;

  if (pr == 0 || pr == 57) {
    for (int i = tid; i < 928; i += 256)
      *(f16x8*)(orow + (size_t)i * 8) = (f16x8){};
    return;
  }
  const int h = pr - 1;
  const int wave = tid >> 6, lane = tid & 63;
  if (tid < 32) {                         // pad columns px=0 and px=57
    int px = (tid < 16) ? 0 : 57;
    int cg = tid & 15;
    *(f16x8*)(orow + (size_t)px * CIN + cg * 8) = (f16x8){};
  }
  if (lane < 56) {
    const float* xb = x + (size_t)b * CIN * HW + (size_t)h * WW + lane;
    f16* op = orow + (size_t)(lane + 1) * CIN;
    #pragma unroll
    for (int cg = 0; cg < 4; ++cg) {
      const int c0 = (wave * 4 + cg) * 8;
      f16x8 v;
      #pragma unroll
      for (int j = 0; j < 8; ++j)
        v[j] = (f16)xb[(size_t)(c0 + j) * HW];
      *(f16x8*)(op + c0) = v;
    }
  }
}

// ---------------------------------------------------------------------------
// Prepass 2: w (OIHW f32) -> sign -> f16, baked as the exact LDS images the
// main kernel stages linearly. Per (K-tile t, co-half coh): 8 KB image,
// 64 physical rows x 128B, 2 co packed per row, chunk swizzle c_phys =
// c_log ^ (R&7). Logical: co = coh*128 + 2R + (c_log>>2),
// k-in-tile = (c_log&3)*8 + h_i; channel = (t&3)*32 + k, kidx = t>>2.
// ---------------------------------------------------------------------------
__global__ __launch_bounds__(256) void wprep_kernel(const float* __restrict__ w,
                                                    f16* __restrict__ wt) {
  int o = blockIdx.x * 256 + threadIdx.x;   // 294912 exact (36*2*4096)
  int tile  = o >> 13;
  int coh   = (o >> 12) & 1;
  int rem   = o & 4095;
  int R     = rem >> 6;
  int hr    = rem & 63;
  int c_log = (hr >> 3) ^ (R & 7);
  int co    = coh * 128 + 2 * R + (c_log >> 2);
  int kl    = (c_log & 3) * 8 + (hr & 7);
  int kidx  = tile >> 2, q = tile & 3;
  int ch    = q * 32 + kl;
  float v = w[(size_t)co * 1152 + ch * 9 + kidx];
  wt[o] = (f16)((v > 0.f) ? 1.f : (v < 0.f ? -1.f : 0.f));
}

// ---------------------------------------------------------------------------
// Main implicit-GEMM: block tile 256 px x 128 co, K=1152, 36 K-tiles of BK=32.
// 4 waves (2M x 2N), wave-tile 128 px x 64 co. Dbuf LDS 48 KB.
// T3/T4 pipeline: 2 phases per K-tile, counted vmcnt (3/2, never 0 mid-loop),
// stage tile t+1 split across phases; T5 setprio; T2-style chunk swizzle
// (2-px-packed 128B rows -> 2-way-only bank aliasing = free).
// ---------------------------------------------------------------------------
__global__ __launch_bounds__(256) void bconv_main(
    const f16* __restrict__ xp, const f16* __restrict__ wt,
    const float* __restrict__ bias, float* __restrict__ out) {
  __shared__ __align__(16) char LDS[49152];   // A: 2x16KB @0, B: 2x8KB @32768
  const int tid = threadIdx.x;
  const int bid = blockIdx.x;                 // 784 = 8*98 (bijective XCD swz)
  const int swz = (bid & 7) * 98 + (bid >> 3);
  const int pxt = swz >> 1;
  const int coh = swz & 1;
  const int p0  = pxt * 256;

  // ---- staging maps: round r fills phys rows [32r,32r+32) of its image ----
  const int row8  = tid >> 3;                 // 0..31
  const int c_log = (tid & 7) ^ (row8 & 7);
  const char* srcA[4];
  #pragma unroll
  for (int r = 0; r < 4; ++r) {
    int p  = r * 64 + 2 * row8 + (c_log >> 2);
    int pg = p0 + p;
    int b = pg / HW, rr = pg % HW;
    int h = rr / WW, w = rr % WW;
    srcA[r] = (const char*)xp +
              2 * ((size_t)b * XPLANE + (size_t)((h + 1) * 58 + (w + 1)) * CIN) +
              (c_log & 3) * 16;
  }
  const char* wtB = (const char*)wt + coh * 8192 + (tid << 4);
  char* L = (char*)LDS;
  const int dstT = tid << 4;

  // ---- fragment maps ----
  const int wave = tid >> 6, lane = tid & 63;
  const int wm = wave >> 1, wn = wave & 1;    // 2M x 2N
  const int l15 = lane & 15, l4 = lane >> 4;
  const int lane_off = (l15 >> 1) * 128 + ((((l15 & 1) << 2) + l4) ^ (l15 >> 1)) * 16;
  const int xbase = wm * 8192 + lane_off;         // + cb*16384 + mIdx*1024
  const int wbase = 32768 + wn * 4096 + lane_off; // + cb*8192  + n*1024

  f32x4 acc[8][4];
  #pragma unroll
  for (int i = 0; i < 8; ++i)
    #pragma unroll
    for (int j = 0; j < 4; ++j) acc[i][j] = (f32x4){0.f, 0.f, 0.f, 0.f};

  // ---- prologue: stage tile 0 into buf0, order A0,A2,B0,B1,A1,A3 ----
  // tile0: kidx=0 (dh=dw=-1), q=0 -> src offset -59*256 = -15104
  gload16(srcA[0] - 15104, L + 0     + dstT);
  gload16(srcA[2] - 15104, L + 8192  + dstT);
  gload16(wtB + 0,         L + 32768 + 0    + dstT);
  gload16(wtB + 4096,      L + 32768 + 4096 + dstT);
  gload16(srcA[1] - 15104, L + 4096  + dstT);
  gload16(srcA[3] - 15104, L + 12288 + dstT);
  asm volatile("s_waitcnt vmcnt(2)" ::: "memory");
  asm volatile("s_barrier" ::: "memory");

  #pragma unroll 1
  for (int t = 0; t < 36; ++t) {
    const int cb = t & 1, sb = cb ^ 1;
    const bool st = (t < 35);
    const int tn  = t + 1;
    const int kidn = tn >> 2, qn = tn & 3;
    const int dhn = kidn / 3 - 1, dwn = kidn - (kidn / 3) * 3 - 1;
    const long toffA = (long)(dhn * 58 + dwn) * 256 + qn * 64;
    const char* wsrc = wtB + (size_t)tn * 16384;
    char* Adst = L + sb * 16384;
    char* Bdst = L + 32768 + sb * 8192;
    const char* Ard = L + cb * 16384;
    const char* Wrd = L + cb * 8192;

    f16x8 wf[4];                    // held across both phases
    // ======== phase 0 (jb=0): px frags 0..3 ========
    {
      f16x8 xf[4];
      #pragma unroll
      for (int mm = 0; mm < 4; ++mm)
        xf[mm] = *(const f16x8*)(Ard + xbase + mm * 1024);
      #pragma unroll
      for (int n = 0; n < 4; ++n)
        wf[n] = *(const f16x8*)(Wrd + wbase + n * 1024);
      if (st) {
        gload16(srcA[0] + toffA, Adst + 0    + dstT);
        gload16(srcA[2] + toffA, Adst + 8192 + dstT);
        gload16(wsrc,            Bdst + dstT);
      }
      asm volatile("s_barrier" ::: "memory");
      asm volatile("s_waitcnt lgkmcnt(0)" ::: "memory");
      __builtin_amdgcn_sched_barrier(0);
      __builtin_amdgcn_s_setprio(1);
      #pragma unroll
      for (int mm = 0; mm < 4; ++mm)
        #pragma unroll
        for (int n = 0; n < 4; ++n)
          acc[mm][n] = __builtin_amdgcn_mfma_f32_16x16x32_f16(wf[n], xf[mm], acc[mm][n], 0, 0, 0);
      __builtin_amdgcn_s_setprio(0);
      __builtin_amdgcn_sched_barrier(0);
      if (st) asm volatile("s_waitcnt vmcnt(3)" ::: "memory");  // A1,A3 of tile t landed
      else    asm volatile("s_waitcnt vmcnt(0)" ::: "memory");
      asm volatile("s_barrier" ::: "memory");
    }
    // ======== phase 1 (jb=1): px frags 4..7 ========
    {
      f16x8 xf[4];
      #pragma unroll
      for (int mm = 0; mm < 4; ++mm)
        xf[mm] = *(const f16x8*)(Ard + xbase + (4 + mm) * 1024);
      if (st) {
        gload16(wsrc + 4096,     Bdst + 4096  + dstT);
        gload16(srcA[1] + toffA, Adst + 4096  + dstT);
        gload16(srcA[3] + toffA, Adst + 12288 + dstT);
      }
      asm volatile("s_barrier" ::: "memory");
      asm volatile("s_waitcnt lgkmcnt(0)" ::: "memory");
      __builtin_amdgcn_sched_barrier(0);
      __builtin_amdgcn_s_setprio(1);
      #pragma unroll
      for (int mm = 0; mm < 4; ++mm)
        #pragma unroll
        for (int n = 0; n < 4; ++n)
          acc[4 + mm][n] = __builtin_amdgcn_mfma_f32_16x16x32_f16(wf[n], xf[mm], acc[4 + mm][n], 0, 0, 0);
      __builtin_amdgcn_s_setprio(0);
      __builtin_amdgcn_sched_barrier(0);
      if (st) asm volatile("s_waitcnt vmcnt(2)" ::: "memory");  // A0,A2,B0,B1 of t+1 landed
      asm volatile("s_barrier" ::: "memory");
    }
  }

  // ---- epilogue: D col(l15)=px -> coalesced 64B runs along px ----
  #pragma unroll
  for (int m = 0; m < 8; ++m) {
    const int pg = p0 + wm * 128 + m * 16 + l15;
    const int bo = pg / HW;
    const int pr = pg % HW;
    float* ob = out + (size_t)bo * (COUT * HW) + pr;
    #pragma unroll
    for (int n = 0; n < 4; ++n) {
      const int cb2 = coh * 128 + wn * 64 + n * 16 + l4 * 4;
      #pragma unroll
      for (int r = 0; r < 4; ++r)
        ob[(size_t)(cb2 + r) * HW] = acc[m][n][r] + bias[cb2 + r];
    }
  }
}

extern "C" void kernel_launch(void* const* d_in, const int* in_sizes, int n_in,
                              void* d_out, int out_size, void* d_ws, size_t ws_size,
                              hipStream_t stream) {
  const float* x    = (const float*)d_in[0];
  const float* w    = (const float*)d_in[1];
  const float* bias = (const float*)d_in[2];
  float* out = (float*)d_out;

  f16* xp = (f16*)d_ws;                       // 32*430592 halves = 27.56 MB
  f16* wt = xp + (size_t)32 * XPLANE;         // 294912 halves    = 0.59 MB

  xpad_kernel<<<1856, 256, 0, stream>>>(x, xp);
  wprep_kernel<<<1152, 256, 0, stream>>>(w, wt);
  bconv_main<<<784, 256, 0, stream>>>(xp, wt, bias, out);
}

// Round 6
// 240.083 us; speedup vs baseline: 1.2800x; 1.0754x over previous
//
#include <hip/hip_runtime.h>
#include <cstdint>
#include <cstddef>

typedef _Float16 f16;
typedef _Float16 f16x8 __attribute__((ext_vector_type(8)));
typedef float    f32x4 __attribute__((ext_vector_type(4)));

#define CIN    128
#define COUT   256
#define HH     56
#define WW     56
#define HW     3136           // 56*56
#define XPLANE (3364*128)     // 58*58 padded plane * CIN halves

__device__ __forceinline__ void gload16(const void* g, void* l) {
  __builtin_amdgcn_global_load_lds((const __attribute__((address_space(1))) unsigned int*)g,
                                   (__attribute__((address_space(3))) unsigned int*)l,
                                   16, 0, 0);
}

// ---------------------------------------------------------------------------
// Prepass 1 (LDS-free, proven R3): x (NCHW f32) -> zero-padded NHWC f16.
// ---------------------------------------------------------------------------
__global__ __launch_bounds__(256) void xpad_kernel(const float* __restrict__ x,
                                                   f16* __restrict__ xp) {
  const int bid = blockIdx.x;             // 32*58 = 1856
  const int pr  = bid % 58;
  const int b   = bid / 58;
  const int tid = threadIdx.x;
  f16* orow = xp + (size_t)b * XPLANE + (size_t)pr * 58 * CIN;

  if (pr == 0 || pr == 57) {
    for (int i = tid; i < 928; i += 256)
      *(f16x8*)(orow + (size_t)i * 8) = (f16x8){};
    return;
  }
  const int h = pr - 1;
  const int wave = tid >> 6, lane = tid & 63;
  if (tid < 32) {                         // pad columns px=0 and px=57
    int px = (tid < 16) ? 0 : 57;
    int cg = tid & 15;
    *(f16x8*)(orow + (size_t)px * CIN + cg * 8) = (f16x8){};
  }
  if (lane < 56) {
    const float* xb = x + (size_t)b * CIN * HW + (size_t)h * WW + lane;
    f16* op = orow + (size_t)(lane + 1) * CIN;
    #pragma unroll
    for (int cg = 0; cg < 4; ++cg) {
      const int c0 = (wave * 4 + cg) * 8;
      f16x8 v;
      #pragma unroll
      for (int j = 0; j < 8; ++j)
        v[j] = (f16)xb[(size_t)(c0 + j) * HW];
      *(f16x8*)(op + c0) = v;
    }
  }
}

// ---------------------------------------------------------------------------
// Prepass 2 (verified R5): w (OIHW f32) -> sign -> f16, baked as the exact
// swizzled LDS images. Per (K-tile t, co-half coh): 8 KB image, 64 rows x
// 128B, 2 co per row, chunk swizzle c_phys = c_log ^ (R&7).
// ---------------------------------------------------------------------------
__global__ __launch_bounds__(256) void wprep_kernel(const float* __restrict__ w,
                                                    f16* __restrict__ wt) {
  int o = blockIdx.x * 256 + threadIdx.x;   // 294912 exact (36*2*4096)
  int tile  = o >> 13;
  int coh   = (o >> 12) & 1;
  int rem   = o & 4095;
  int R     = rem >> 6;
  int hr    = rem & 63;
  int c_log = (hr >> 3) ^ (R & 7);
  int co    = coh * 128 + 2 * R + (c_log >> 2);
  int kl    = (c_log & 3) * 8 + (hr & 7);
  int kidx  = tile >> 2, q = tile & 3;
  int ch    = q * 32 + kl;
  float v = w[(size_t)co * 1152 + ch * 9 + kidx];
  wt[o] = (f16)((v > 0.f) ? 1.f : (v < 0.f ? -1.f : 0.f));
}

// ---------------------------------------------------------------------------
// Main implicit-GEMM: block tile 256 px x 128 co, K=1152, 36 K-tiles of BK=32.
// 4 waves (2M x 2N), wave-tile 128 px x 64 co. Dbuf LDS 48 KB.
// Minimum 2-phase schedule (T3 recipe): per tile
//   issue STAGE(t+1) -> ds_read(t) -> lgkmcnt(0) -> 32 MFMA -> vmcnt(0) -> bar
// ONE barrier per tile; staged loads drain after a full tile of compute.
// ---------------------------------------------------------------------------
__global__ __launch_bounds__(256) void bconv_main(
    const f16* __restrict__ xp, const f16* __restrict__ wt,
    const float* __restrict__ bias, float* __restrict__ out) {
  __shared__ __align__(16) char LDS[49152];   // A: 2x16KB @0, B: 2x8KB @32768
  const int tid = threadIdx.x;
  const int bid = blockIdx.x;                 // 784 = 8*98 (bijective XCD swz)
  const int swz = (bid & 7) * 98 + (bid >> 3);
  const int pxt = swz >> 1;
  const int coh = swz & 1;
  const int p0  = pxt * 256;

  // ---- staging maps (verified R5) ----
  const int row8  = tid >> 3;                 // 0..31
  const int c_log = (tid & 7) ^ (row8 & 7);
  const char* srcA[4];
  #pragma unroll
  for (int r = 0; r < 4; ++r) {
    int p  = r * 64 + 2 * row8 + (c_log >> 2);
    int pg = p0 + p;
    int b = pg / HW, rr = pg % HW;
    int h = rr / WW, w = rr % WW;
    srcA[r] = (const char*)xp +
              2 * ((size_t)b * XPLANE + (size_t)((h + 1) * 58 + (w + 1)) * CIN) +
              (c_log & 3) * 16;
  }
  const char* wtB = (const char*)wt + coh * 8192 + (tid << 4);
  char* L = (char*)LDS;
  const int dstT = tid << 4;

  // ---- fragment maps (verified R5) ----
  const int wave = tid >> 6, lane = tid & 63;
  const int wm = wave >> 1, wn = wave & 1;    // 2M x 2N
  const int l15 = lane & 15, l4 = lane >> 4;
  const int lane_off = (l15 >> 1) * 128 + ((((l15 & 1) << 2) + l4) ^ (l15 >> 1)) * 16;
  const int xbase = wm * 8192 + lane_off;         // + mIdx*1024 (+16384 dbuf)
  const int wbase = 32768 + wn * 4096 + lane_off; // + n*1024    (+8192 dbuf)

  f32x4 acc[8][4];
  #pragma unroll
  for (int i = 0; i < 8; ++i)
    #pragma unroll
    for (int j = 0; j < 4; ++j) acc[i][j] = (f32x4){0.f, 0.f, 0.f, 0.f};

  // ---- prologue: stage tile 0 into buf0 (kidx=0: dh=dw=-1,q=0 -> -15104) ----
  #pragma unroll
  for (int r = 0; r < 4; ++r)
    gload16(srcA[r] - 15104, L + r * 4096 + dstT);
  gload16(wtB,        L + 32768 + dstT);
  gload16(wtB + 4096, L + 32768 + 4096 + dstT);
  asm volatile("s_waitcnt vmcnt(0)" ::: "memory");
  asm volatile("s_barrier" ::: "memory");

  #pragma unroll 1
  for (int t = 0; t < 36; ++t) {
    const int cbA = (t & 1) << 14;            // 0 / 16384
    const int sbA = cbA ^ 16384;
    const int cbB = (t & 1) << 13;            // 0 / 8192
    const int sbB = cbB ^ 8192;

    // ---- issue STAGE(t+1) first (covered by this tile's compute) ----
    if (t < 35) {
      const int tn = t + 1;
      const int kidn = tn >> 2, qn = tn & 3;
      const int dhn = kidn / 3 - 1, dwn = kidn - (kidn / 3) * 3 - 1;
      const long toffA = (long)(dhn * 58 + dwn) * 256 + qn * 64;
      const char* wsrc = wtB + (size_t)tn * 16384;
      #pragma unroll
      for (int r = 0; r < 4; ++r)
        gload16(srcA[r] + toffA, L + sbA + r * 4096 + dstT);
      gload16(wsrc,        L + 32768 + sbB + dstT);
      gload16(wsrc + 4096, L + 32768 + sbB + 4096 + dstT);
    }

    // ---- ds_read current tile: 4 wf + 8 xf (two batches to cap VGPRs) ----
    const char* Ard = L + cbA;
    const char* Wrd = L + cbB;                // wbase already includes 32768
    f16x8 wf[4];
    #pragma unroll
    for (int n = 0; n < 4; ++n)
      wf[n] = *(const f16x8*)(Wrd + wbase + n * 1024);
    {
      f16x8 xf[4];
      #pragma unroll
      for (int mm = 0; mm < 4; ++mm)
        xf[mm] = *(const f16x8*)(Ard + xbase + mm * 1024);
      asm volatile("s_waitcnt lgkmcnt(0)" ::: "memory");
      __builtin_amdgcn_sched_barrier(0);
      __builtin_amdgcn_s_setprio(1);
      #pragma unroll
      for (int mm = 0; mm < 4; ++mm)
        #pragma unroll
        for (int n = 0; n < 4; ++n)
          acc[mm][n] = __builtin_amdgcn_mfma_f32_16x16x32_f16(wf[n], xf[mm], acc[mm][n], 0, 0, 0);
      __builtin_amdgcn_s_setprio(0);
    }
    {
      f16x8 xf[4];
      #pragma unroll
      for (int mm = 0; mm < 4; ++mm)
        xf[mm] = *(const f16x8*)(Ard + xbase + (4 + mm) * 1024);
      asm volatile("s_waitcnt lgkmcnt(0)" ::: "memory");
      __builtin_amdgcn_sched_barrier(0);
      __builtin_amdgcn_s_setprio(1);
      #pragma unroll
      for (int mm = 0; mm < 4; ++mm)
        #pragma unroll
        for (int n = 0; n < 4; ++n)
          acc[4 + mm][n] = __builtin_amdgcn_mfma_f32_16x16x32_f16(wf[n], xf[mm], acc[4 + mm][n], 0, 0, 0);
      __builtin_amdgcn_s_setprio(0);
    }
    __builtin_amdgcn_sched_barrier(0);
    // ---- drain staged loads (landed long ago) + single barrier ----
    asm volatile("s_waitcnt vmcnt(0)" ::: "memory");
    asm volatile("s_barrier" ::: "memory");
  }

  // ---- epilogue (verified R5): D col(l15)=px -> coalesced stores ----
  #pragma unroll
  for (int m = 0; m < 8; ++m) {
    const int pg = p0 + wm * 128 + m * 16 + l15;
    const int bo = pg / HW;
    const int pr = pg % HW;
    float* ob = out + (size_t)bo * (COUT * HW) + pr;
    #pragma unroll
    for (int n = 0; n < 4; ++n) {
      const int cb2 = coh * 128 + wn * 64 + n * 16 + l4 * 4;
      #pragma unroll
      for (int r = 0; r < 4; ++r)
        ob[(size_t)(cb2 + r) * HW] = acc[m][n][r] + bias[cb2 + r];
    }
  }
}

extern "C" void kernel_launch(void* const* d_in, const int* in_sizes, int n_in,
                              void* d_out, int out_size, void* d_ws, size_t ws_size,
                              hipStream_t stream) {
  const float* x    = (const float*)d_in[0];
  const float* w    = (const float*)d_in[1];
  const float* bias = (const float*)d_in[2];
  float* out = (float*)d_out;

  f16* xp = (f16*)d_ws;                       // 32*430592 halves = 27.56 MB
  f16* wt = xp + (size_t)32 * XPLANE;         // 294912 halves    = 0.59 MB

  xpad_kernel<<<1856, 256, 0, stream>>>(x, xp);
  wprep_kernel<<<1152, 256, 0, stream>>>(w, wt);
  bconv_main<<<784, 256, 0, stream>>>(xp, wt, bias, out);
}